// Round 9
// baseline (156.467 us; speedup 1.0000x reference)
//
#include <hip/hip_runtime.h>
#include <hip/hip_bf16.h>

// Weighted BCE over predict [N=8, C=19, H=512, W=1024] fp32 probs,
// target [N,H,W] int32 labels -> single fp32 scalar.
//
// result = (neg_num*S_pos + pos_num*S_neg) / ((pos_num+neg_num)*mask_cnt*C)
//
// R4-R7 lesson: every access-pattern restructure converges at ~3.2 TB/s
// effective read; copy ubench (6.29 TB/s) is read+write COMBINED (~3.15
// each way) -> likely near the pure-read ceiling. R8 (fixed compile):
// (a) fuse label-read + counting into the sweep (each thread owns its 8
// pixels' labels: 2 x int4 loaded once) -> pack kernel gone; (b)
// nontemporal predict loads via ext_vector_type(4) float (the builtin
// rejects HIP_vector_type pointers).

constexpr int CLS    = 19;
constexpr int HWSZ   = 512 * 1024;        // pixels per plane
constexpr int CHW4   = HWSZ / 4;          // float4/int4 chunks per plane
constexpr int SLABC  = CLS * CHW4;        // chunks per image
constexpr int IGNORE = 255;
constexpr int GPI    = 65536;             // threads per image = CHW4/2
constexpr int NWIN   = 2 * CLS;           // 38 windows per slab

typedef float f32x4 __attribute__((ext_vector_type(4)));

// ws: f[0]=S_valid_log2, f[1]=S_neg_log2, u[2]=pos, u[3]=neg, u[4]=mask

__global__ void bce_init(float* wsf) {
    if (threadIdx.x < 8) wsf[threadIdx.x] = 0.0f;
}

// ---- fused hot kernel: labels once per thread, counts in-kernel ----
__global__ __launch_bounds__(256) void bce_fused(
    const f32x4* __restrict__ pred4,
    const int4*  __restrict__ tgt4,
    float* __restrict__ wsf, unsigned* __restrict__ wsu)
{
    const int b  = blockIdx.x;
    const int ni = b >> 8;                         // image (scalar)
    const int g  = ((b & 255) << 8) | threadIdx.x; // [0, GPI)

    const f32x4* slab = pred4 + (size_t)ni * SLABC;
    const int4*  labs = tgt4  + (size_t)ni * CHW4;

    // labels for this thread's 8 pixels (hw4 = g and g+GPI), loaded ONCE;
    // each int4 is owned by exactly one thread per image -> counts exact.
    int4 t0 = labs[g];
    int4 t1 = labs[g + GPI];
    int   t[8] = { t0.x, t0.y, t0.z, t0.w, t1.x, t1.y, t1.z, t1.w };
    float wv[8], wn[8];
    unsigned cp = 0, cn = 0, cm = 0;
    #pragma unroll
    for (int j = 0; j < 8; ++j) {
        bool val = (t[j] >= 0) && (t[j] != IGNORE);
        cp += (t[j] > 0)  ? 1u : 0u;     // reference counts ALL t>0 as pos
        cn += (t[j] == 0) ? 1u : 0u;
        cm += val         ? 1u : 0u;
        wv[j] = val         ? 1.0f : 0.0f;
        wn[j] = (t[j] == 0) ? 1.0f : 0.0f;
        // invalid labels (255/neg) never equal c in [0,19) -> x=1-p, weight 0
    }

    float sv = 0.f, sn = 0.f;

    // 38 windows in batches of 8,8,8,8,6; all indices compile-time.
    #pragma unroll
    for (int kb = 0; kb < NWIN; kb += 8) {
        const int cnt = (NWIN - kb) < 8 ? (NWIN - kb) : 8;
        f32x4 p[8];
        #pragma unroll
        for (int m = 0; m < 8; ++m)
            if (m < cnt)
                p[m] = __builtin_nontemporal_load(&slab[(size_t)(kb + m) * GPI + g]);
        #pragma unroll
        for (int m = 0; m < 8; ++m) {
            if (m < cnt) {
                const int k  = kb + m;
                const int c  = k >> 1;            // plane, compile-time
                const int wo = (k & 1) * 4;
                const float pj[4] = { p[m].x, p[m].y, p[m].z, p[m].w };
                #pragma unroll
                for (int j = 0; j < 4; ++j) {
                    float q = 1.0f - pj[j];
                    float x = (t[wo + j] == c) ? pj[j] : q;  // x >= 1e-4
                    float l = __log2f(x);
                    sv = fmaf(wv[wo + j], l, sv);
                    sn = fmaf(wn[wo + j], l, sn);
                }
            }
        }
    }

    // ---- wave reduction ----
    #pragma unroll
    for (int off = 32; off > 0; off >>= 1) {
        sv += __shfl_down(sv, off);
        sn += __shfl_down(sn, off);
        cp += __shfl_down(cp, off);
        cn += __shfl_down(cn, off);
        cm += __shfl_down(cm, off);
    }
    __shared__ float    lsv[4], lsn[4];
    __shared__ unsigned lcp[4], lcn[4], lcm[4];
    int lane = threadIdx.x & 63, wid = threadIdx.x >> 6;
    if (lane == 0) {
        lsv[wid] = sv; lsn[wid] = sn;
        lcp[wid] = cp; lcn[wid] = cn; lcm[wid] = cm;
    }
    __syncthreads();
    if (threadIdx.x == 0) {
        float bv = 0.f, bn = 0.f;
        unsigned up = 0, un = 0, um = 0;
        #pragma unroll
        for (int i = 0; i < 4; ++i) {
            bv += lsv[i]; bn += lsn[i];
            up += lcp[i]; un += lcn[i]; um += lcm[i];
        }
        atomicAdd(&wsf[0], bv);
        atomicAdd(&wsf[1], bn);
        atomicAdd(&wsu[2], up);
        atomicAdd(&wsu[3], un);
        atomicAdd(&wsu[4], um);
    }
}

// ---- general fallback (R4 structure) ----
__global__ __launch_bounds__(256) void bce_count(
    const int* __restrict__ tgt, unsigned* __restrict__ wsu, int npix4)
{
    int tid    = blockIdx.x * blockDim.x + threadIdx.x;
    int stride = gridDim.x * blockDim.x;
    unsigned cp = 0, cn = 0, cm = 0;
    for (int i = tid; i < npix4; i += stride) {
        int4 t4 = ((const int4*)tgt)[i];
        int  t[4] = { t4.x, t4.y, t4.z, t4.w };
        #pragma unroll
        for (int j = 0; j < 4; ++j) {
            cp += (t[j] > 0) ? 1u : 0u;
            cn += (t[j] == 0) ? 1u : 0u;
            cm += ((t[j] >= 0) && (t[j] != IGNORE)) ? 1u : 0u;
        }
    }
    #pragma unroll
    for (int off = 32; off > 0; off >>= 1) {
        cp += __shfl_down(cp, off);
        cn += __shfl_down(cn, off);
        cm += __shfl_down(cm, off);
    }
    __shared__ unsigned lcp[4], lcn[4], lcm[4];
    int lane = threadIdx.x & 63, wid = threadIdx.x >> 6;
    if (lane == 0) { lcp[wid] = cp; lcn[wid] = cn; lcm[wid] = cm; }
    __syncthreads();
    if (threadIdx.x == 0) {
        unsigned up = 0, un = 0, um = 0;
        #pragma unroll
        for (int i = 0; i < 4; ++i) { up += lcp[i]; un += lcn[i]; um += lcm[i]; }
        atomicAdd(&wsu[2], up);
        atomicAdd(&wsu[3], un);
        atomicAdd(&wsu[4], um);
    }
}

__global__ __launch_bounds__(256) void bce_stream_div(
    const float* __restrict__ pred,
    const int*   __restrict__ tgt,
    float*       __restrict__ wsf,
    int nChunks)
{
    const int tloc = threadIdx.x;
    float sv = 0.f, sn = 0.f;
    for (int base = blockIdx.x * 1024; base < nChunks; base += gridDim.x * 1024) {
        #pragma unroll
        for (int m = 0; m < 4; ++m) {
            int f = base + m * 256 + tloc;
            if (f >= nChunks) break;
            int plane   = f >> 17;
            int hw4     = f & (CHW4 - 1);
            unsigned ni = (unsigned)plane / (unsigned)CLS;
            int c       = plane - (int)ni * CLS;
            float4 p4 = ((const float4*)pred)[f];
            int4   t4 = ((const int4*)tgt)[(int)ni * CHW4 + hw4];
            const int   tj[4] = { t4.x, t4.y, t4.z, t4.w };
            const float pj[4] = { p4.x, p4.y, p4.z, p4.w };
            #pragma unroll
            for (int j = 0; j < 4; ++j) {
                bool valid = (tj[j] >= 0) && (tj[j] != IGNORE);
                float wvx = valid ? 1.0f : 0.0f;
                float wnx = (tj[j] == 0) ? 1.0f : 0.0f;
                float q = 1.0f - pj[j];
                float x = (tj[j] == c) ? pj[j] : q;
                x = fminf(fmaxf(x, 1e-12f), 1.0f);
                float l = __log2f(x);
                sv = fmaf(wvx, l, sv);
                sn = fmaf(wnx, l, sn);
            }
        }
    }
    #pragma unroll
    for (int off = 32; off > 0; off >>= 1) {
        sv += __shfl_down(sv, off);
        sn += __shfl_down(sn, off);
    }
    __shared__ float lsv[4], lsn[4];
    int lane = threadIdx.x & 63, wid = threadIdx.x >> 6;
    if (lane == 0) { lsv[wid] = sv; lsn[wid] = sn; }
    __syncthreads();
    if (threadIdx.x == 0) {
        float bv = 0.f, bn = 0.f;
        #pragma unroll
        for (int i = 0; i < 4; ++i) { bv += lsv[i]; bn += lsn[i]; }
        atomicAdd(&wsf[0], bv);
        atomicAdd(&wsf[1], bn);
    }
}

__global__ void bce_final(const float* wsf, const unsigned* wsu, float* out) {
    if (threadIdx.x == 0 && blockIdx.x == 0) {
        const double LN2 = 0.6931471805599453;
        double svld = (double)wsf[0];          // sum log2 over valid pixels
        double sngl = (double)wsf[1];          // sum log2 over t==0 pixels
        double spos = svld - sngl;             // valid & t>0
        double pn   = (double)wsu[2];
        double nn   = (double)wsu[3];
        double mk   = (double)wsu[4];
        double sum  = pn + nn;
        double denom = sum * mk * (double)CLS;
        out[0] = (denom > 0.0)
                   ? (float)(-LN2 * (nn * spos + pn * sngl) / denom)
                   : 0.0f;
    }
}

extern "C" void kernel_launch(void* const* d_in, const int* in_sizes, int n_in,
                              void* d_out, int out_size, void* d_ws, size_t ws_size,
                              hipStream_t stream) {
    const float* pred = (const float*)d_in[0];
    const int*   tgt  = (const int*)d_in[1];
    float*       out  = (float*)d_out;

    float*    wsf = (float*)d_ws;
    unsigned* wsu = (unsigned*)d_ws;

    int nElem = in_sizes[0];          // 8*19*512*1024
    int npix  = in_sizes[1];          // 8*512*1024
    int npix4 = npix >> 2;

    bool fast = (nElem == 8 * SLABC * 4) && (npix == 8 * HWSZ);

    bce_init<<<1, 64, 0, stream>>>(wsf);
    if (fast) {
        bce_fused<<<8 * 256, 256, 0, stream>>>((const f32x4*)pred,
                                               (const int4*)tgt, wsf, wsu);
    } else {
        int nChunks = nElem >> 2;
        bce_count<<<1024, 256, 0, stream>>>(tgt, wsu, npix4);
        bce_stream_div<<<2048, 256, 0, stream>>>(pred, tgt, wsf, nChunks);
    }
    bce_final<<<1, 64, 0, stream>>>(wsf, wsu, out);
}